// Round 2
// baseline (26018.796 us; speedup 1.0000x reference)
//
#include <hip/hip_runtime.h>
#include <hip/hip_bf16.h>

// Problem constants
#define Bb   128
#define Tt   800
#define Uu   64
#define Cc   80
#define Nn   512
#define KP   608      // padded K = 3 + 80 + 512 -> 19*32
#define NBLK 128      // persistent blocks
#define KSTR 632      // ldsB row stride (shorts)
#define LBL  (16*KSTR) // lo-limb offset inside ldsB (shorts)

#define AL   (Bb*KP)   // amat limb stride (shorts) = 77824
#define ABUF (2*AL)    // amat buffer stride (shorts)
#define WL   (2048*KP) // wcb limb stride (shorts)

#define OUT_PHI 52428800u   // 128*800*512
#define OUT_W   58982400u   // + 128*800*64

// ws byte offsets
#define WS_WCB   0u         // 2 limb * 2048 * 608 * 2B = 4,980,736
#define WS_AMAT  4980736u   // 2 buf * 2 limb * 128 * 608 * 2B = 1,245,184
#define WS_KAP   6225920u   // 128*10*4 = 5,120
#define WS_WWT   6231040u   // [30][512] f32 transposed W_win = 61,440
#define WS_CTR   6292480u   // barrier counter

typedef __attribute__((ext_vector_type(8))) short short8;
typedef __attribute__((ext_vector_type(4))) float f32x4;

__device__ __forceinline__ float b2f(unsigned short u){ unsigned int i = ((unsigned int)u)<<16; float f; __builtin_memcpy(&f,&i,4); return f; }
__device__ __forceinline__ unsigned short f2b(float f){ __hip_bfloat16 h = __float2bfloat16(f); unsigned short u; __builtin_memcpy(&u,&h,2); return u; }
__device__ __forceinline__ float sigm(float v){ return 1.f/(1.f + expf(-v)); }

__device__ __forceinline__ void gbar(int* ctr, int target) {
    __syncthreads();
    if (threadIdx.x == 0) {
        __threadfence();                       // release our writes (agent scope)
        atomicAdd(ctr, 1);                     // device-scope arrive
        while (__hip_atomic_load(ctr, __ATOMIC_RELAXED, __HIP_MEMORY_SCOPE_AGENT) < target)
            __builtin_amdgcn_s_sleep(1);
        __threadfence();                       // acquire others' writes
    }
    __syncthreads();
}

// ---- prep: combined weights -> bf16 hi/lo limbs; W_win transpose (f32) ----
__global__ void prep_weights(const float* __restrict__ Wx, const float* __restrict__ Wh,
                             const float* __restrict__ Wwin,
                             unsigned short* __restrict__ wcb, float* __restrict__ wwt) {
    int i = blockIdx.x*256 + threadIdx.x;
    const int n1 = 2048*KP;                       // 1,245,184
    if (i < n1) {
        int col = i / KP, k = i % KP;
        float v;
        if (k < 83)       v = Wx[k*2048 + col];        // rows 0..2 = x, 3..82 = w
        else if (k < 595) v = Wh[(k-83)*2048 + col];   // h
        else              v = 0.f;                     // pad
        unsigned short hi = f2b(v);
        wcb[i]      = hi;
        wcb[WL + i] = f2b(v - b2f(hi));
    } else {
        int j = i - n1;
        if (j < 30*512) {
            int c = j >> 9, k = j & 511;
            wwt[j] = Wwin[k*30 + c];                  // [c][k] f32
        }
    }
}

// ---- prep: A-matrix double-buffer (hi/lo), kappa, barrier counter ----
__global__ void prep_state(const float* __restrict__ x, unsigned short* __restrict__ amat,
                           float* __restrict__ kap, int* __restrict__ ctr) {
    int i = blockIdx.x*256 + threadIdx.x;
    const int n1 = 2*Bb*KP;           // (buf, r, k) = 155,648
    if (i < n1) {
        int buf = i / (Bb*KP);
        int r   = (i % (Bb*KP)) / KP;
        int k   = i % KP;
        float v = 0.f;
        if (buf == 0 && k < 3) v = x[r*(Tt*3) + k];    // x[:,0,:]
        unsigned short hi = f2b(v);
        amat[(buf*2 + 0)*AL + r*KP + k] = hi;
        amat[(buf*2 + 1)*AL + r*KP + k] = f2b(v - b2f(hi));
    } else if (i < n1 + Bb*10) {
        kap[i - n1] = 0.f;
    } else if (i == n1 + Bb*10) {
        ctr[0] = 0;
    }
}

__global__ __launch_bounds__(256, 1) void rnn_main(
    const float* __restrict__ x,      // [128][800][3]
    const float* __restrict__ sent,   // [128][64][80]
    const int*   __restrict__ slen,   // [128]
    const float* __restrict__ bias,   // [2048]
    const float* __restrict__ bwin,   // [30]
    const unsigned short* __restrict__ wcb,   // 2 limb x [2048][608]
    const float* __restrict__ wwt,            // [30][512] f32
    unsigned short* __restrict__ amat,        // 2 buf x 2 limb x [128][608]
    float* __restrict__ kap,                  // [128][10]
    int* __restrict__ ctr,
    float* __restrict__ out)
{
    __shared__ unsigned short ldsB[2*16*KSTR]; // weight cols hi|lo (bf16 bits) 40,448 B
    __shared__ float ldsWw[30*516];            // W_win^T [c][k] f32        61,920 B
    __shared__ float ldsSent[Uu*Cc];           // sentence row f32           20,480 B
    __shared__ float ldsH[512];                // h row f32
    __shared__ float ldsWinP[240];             // win partials
    __shared__ float ldsWin[32];
    __shared__ float ldsPhi[Uu];
    __shared__ float ldsBias[16];
    __shared__ float ldsBwin[32];

    const int blk  = blockIdx.x;
    const int tid  = threadIdx.x;
    const int wave = tid >> 6;
    const int lane = tid & 63;
    const int l15  = lane & 15;
    const int lhi  = lane >> 4;
    const int row  = blk;               // phase-B batch row

    // ---- one-time LDS fills ----
    for (int idx = tid; idx < 16*76; idx += 256) {
        int cc = idx / 76, k8 = idx % 76;
        int col = (cc >> 2)*512 + blk*4 + (cc & 3);   // gate*512 + n
        *(short8*)&ldsB[cc*KSTR + k8*8]       = *(const short8*)&wcb[col*KP + k8*8];
        *(short8*)&ldsB[LBL + cc*KSTR + k8*8] = *(const short8*)&wcb[WL + col*KP + k8*8];
    }
    for (int idx = tid; idx < 30*512; idx += 256) {
        int c = idx >> 9, k = idx & 511;
        ldsWw[c*516 + k] = wwt[idx];
    }
    for (int idx = tid; idx < Uu*Cc; idx += 256)
        ldsSent[idx] = sent[row*(Uu*Cc) + idx];
    if (tid < 16) ldsBias[tid] = bias[(tid>>2)*512 + blk*4 + (tid&3)];
    if (tid < 30) ldsBwin[tid] = bwin[tid];
    __syncthreads();

    const int myLen = slen[row];
    float c_reg[2][4] = {{0.f,0.f,0.f,0.f},{0.f,0.f,0.f,0.f}};
    int bar_target = 0;

    for (int t = 0; t < Tt; ++t) {
        const int cur = t & 1, nxt = cur ^ 1;
        const unsigned short* aH  = amat + cur*ABUF;
        const unsigned short* aLo = aH + AL;
        unsigned short*       wH  = amat + nxt*ABUF;
        unsigned short*       wLo = wH + AL;

        // ============ Phase A: z = [x,w,h] @ Wc (split bf16 hi/lo), gates, h ============
        #pragma unroll
        for (int mi = 0; mi < 2; ++mi) {
            const int mt = wave*2 + mi;
            f32x4 acc0 = {0.f,0.f,0.f,0.f};    // hi*hi
            f32x4 acc1 = {0.f,0.f,0.f,0.f};    // hi*lo + lo*hi
            const unsigned short* arH = aH  + (mt*16 + l15)*KP + lhi*8;
            const unsigned short* arL = aLo + (mt*16 + l15)*KP + lhi*8;
            const unsigned short* brH = ldsB + l15*KSTR + lhi*8;
            const unsigned short* brL = ldsB + LBL + l15*KSTR + lhi*8;
            #pragma unroll
            for (int kt = 0; kt < 19; ++kt) {
                short8 ah = *(const short8*)(arH + kt*32);
                short8 al = *(const short8*)(arL + kt*32);
                short8 bh = *(const short8*)(brH + kt*32);
                short8 bl = *(const short8*)(brL + kt*32);
                acc0 = __builtin_amdgcn_mfma_f32_16x16x32_bf16(ah, bh, acc0, 0, 0, 0);
                acc1 = __builtin_amdgcn_mfma_f32_16x16x32_bf16(ah, bl, acc1, 0, 0, 0);
                acc1 = __builtin_amdgcn_mfma_f32_16x16x32_bf16(al, bh, acc1, 0, 0, 0);
            }
            const float bv = ldsBias[l15];
            #pragma unroll
            for (int r = 0; r < 4; ++r) {
                float v   = acc0[r] + acc1[r] + bv;
                float t4  = __shfl_xor(v, 4);
                float t8  = __shfl_xor(v, 8);
                float t12 = __shfl_xor(v, 12);
                // lanes with l15<4: zi=v zf=t4 zg=t8 zo=t12
                float ig = sigm(v), fg = sigm(t4), gg = tanhf(t8), og = sigm(t12);
                float cn = fg * c_reg[mi][r] + ig * gg;
                c_reg[mi][r] = cn;
                float h = og * tanhf(cn);
                if (l15 < 4) {
                    int br = mt*16 + lhi*4 + r;
                    int n  = blk*4 + l15;
                    unsigned short hb = f2b(h);
                    wH [br*KP + 83 + n] = hb;
                    wLo[br*KP + 83 + n] = f2b(h - b2f(hb));
                    out[(size_t)(br*Tt + t)*Nn + n] = h;
                }
            }
        }
        bar_target += NBLK; gbar(ctr, bar_target);

        // ============ Phase B: win, phi, w for batch row = blk ============
        {   // stage h row (hi+lo -> f32) into LDS
            const unsigned short* hH = wH  + row*KP + 83;
            const unsigned short* hL = wLo + row*KP + 83;
            ldsH[tid]       = b2f(hH[tid])       + b2f(hL[tid]);
            ldsH[tid + 256] = b2f(hH[tid + 256]) + b2f(hL[tid + 256]);
        }
        __syncthreads();
        if (tid < 240) {                       // win partials: c = tid/8, k-chunk = tid%8
            int c = tid >> 3, q = tid & 7;
            const float* wwc = &ldsWw[c*516 + q*64];
            const float* hh  = &ldsH[q*64];
            float s = 0.f;
            #pragma unroll
            for (int k = 0; k < 64; ++k) s += hh[k]*wwc[k];
            ldsWinP[tid] = s;
        } else if (tid >= 248 && tid < 251) {  // prefetch x_{t+1}
            if (t + 1 < Tt) {
                int j = tid - 248;
                float xv = x[((size_t)row*Tt + (t+1))*3 + j];
                unsigned short hb = f2b(xv);
                wH [row*KP + j] = hb;
                wLo[row*KP + j] = f2b(xv - b2f(hb));
            }
        }
        __syncthreads();
        if (tid < 30) {
            const float* p = &ldsWinP[tid*8];
            ldsWin[tid] = (((p[0]+p[1])+(p[2]+p[3])) + ((p[4]+p[5])+(p[6]+p[7]))) + ldsBwin[tid];
        }
        __syncthreads();
        if (tid < 64) {                        // phi over u = tid
            float u1 = (float)tid + 1.0f;
            float phi = 0.f;
            #pragma unroll
            for (int k = 0; k < 10; ++k) {
                float a  = expf(ldsWin[k]);
                float be = expf(ldsWin[10+k]);
                float kn = kap[row*10 + k] + expf(ldsWin[20+k]);
                float d  = kn - u1;
                phi += a * expf(-be * d * d);
            }
            if (tid >= myLen) phi = 0.f;
            ldsPhi[tid] = phi;
            out[OUT_PHI + (size_t)(row*Tt + t)*Uu + tid] = phi;
            if (tid < 10)
                kap[row*10 + tid] += expf(ldsWin[20+tid]);
        }
        __syncthreads();
        if (tid < 80) {                        // w = phi . sent
            float s = 0.f;
            #pragma unroll
            for (int u = 0; u < Uu; ++u)
                s += ldsPhi[u] * ldsSent[u*Cc + tid];
            out[OUT_W + (size_t)(row*Tt + t)*Cc + tid] = s;
            unsigned short hb = f2b(s);
            wH [row*KP + 3 + tid] = hb;
            wLo[row*KP + 3 + tid] = f2b(s - b2f(hb));
        }
        bar_target += NBLK; gbar(ctr, bar_target);
    }
}

extern "C" void kernel_launch(void* const* d_in, const int* in_sizes, int n_in,
                              void* d_out, int out_size, void* d_ws, size_t ws_size,
                              hipStream_t stream) {
    (void)in_sizes; (void)n_in; (void)out_size; (void)ws_size;
    const float* x    = (const float*)d_in[0];
    const float* sent = (const float*)d_in[1];
    const int*   sl   = (const int*)d_in[2];
    const float* Wx   = (const float*)d_in[3];
    const float* Wh   = (const float*)d_in[4];
    const float* bias = (const float*)d_in[5];
    const float* Wwin = (const float*)d_in[6];
    const float* bwin = (const float*)d_in[7];

    char* ws = (char*)d_ws;
    unsigned short* wcb  = (unsigned short*)(ws + WS_WCB);
    unsigned short* amat = (unsigned short*)(ws + WS_AMAT);
    float* kap = (float*)(ws + WS_KAP);
    float* wwt = (float*)(ws + WS_WWT);
    int*   ctr = (int*)(ws + WS_CTR);
    float* out = (float*)d_out;

    {
        int total = 2048*KP + 30*512;
        prep_weights<<<(total + 255)/256, 256, 0, stream>>>(Wx, Wh, Wwin, wcb, wwt);
    }
    {
        int total = 2*Bb*KP + Bb*10 + 1;
        prep_state<<<(total + 255)/256, 256, 0, stream>>>(x, amat, kap, ctr);
    }
    rnn_main<<<NBLK, 256, 0, stream>>>(x, sent, sl, bias, bwin, wcb, wwt, amat, kap, ctr, out);
}

// Round 3
// 17945.296 us; speedup vs baseline: 1.4499x; 1.4499x over previous
//
#include <hip/hip_runtime.h>
#include <hip/hip_bf16.h>

// Problem constants
#define Bb   128
#define Tt   800
#define Uu   64
#define Cc   80
#define Nn   512
#define KP   608      // K layout: [w 0..79 | x 80..82 | pad 83..95 | h 96..607]
#define NBLK 128      // persistent blocks
#define KSTR 632      // ldsB row stride (shorts)
#define LBL  (16*KSTR) // lo-limb offset inside ldsB (shorts)
#define WWS  517      // ldsWw row stride (f32, odd -> conflict-free)

#define AL   (Bb*KP)   // amat limb stride (shorts) = 77824
#define ABUF (2*AL)    // amat buffer stride (shorts)
#define WL   (2048*KP) // wcb limb stride (shorts)

#define OUT_PHI 52428800u   // 128*800*512
#define OUT_W   58982400u   // + 128*800*64

// ws byte offsets
#define WS_WCB   0u         // 2 limb * 2048 * 608 * 2B = 4,980,736
#define WS_AMAT  4980736u   // 2 buf * 2 limb * 128 * 608 * 2B = 1,245,184
#define WS_WWT   6225920u   // [30][512] f32 transposed W_win = 61,440
#define WS_CTR   6287360u   // barrier counter

typedef __attribute__((ext_vector_type(8))) short short8;
typedef __attribute__((ext_vector_type(4))) float f32x4;
typedef unsigned long long u64;

__device__ __forceinline__ float b2f(unsigned short u){ unsigned int i = ((unsigned int)u)<<16; float f; __builtin_memcpy(&f,&i,4); return f; }
__device__ __forceinline__ unsigned short f2b(float f){ __hip_bfloat16 h = __float2bfloat16(f); unsigned short u; __builtin_memcpy(&u,&h,2); return u; }
__device__ __forceinline__ float sigm(float v){ return 1.f/(1.f + expf(-v)); }

// MALL-coherent (agent-scope, relaxed) accessors: sc0 sc1 ops, no L2 flush needed
__device__ __forceinline__ u64 ald(const u64* p){ return __hip_atomic_load(p, __ATOMIC_RELAXED, __HIP_MEMORY_SCOPE_AGENT); }
__device__ __forceinline__ void ast8(u64* p, u64 v){ __hip_atomic_store(p, v, __ATOMIC_RELAXED, __HIP_MEMORY_SCOPE_AGENT); }
__device__ __forceinline__ void ast2(unsigned short* p, unsigned short v){ __hip_atomic_store(p, v, __ATOMIC_RELAXED, __HIP_MEMORY_SCOPE_AGENT); }

// Grid barrier WITHOUT cache flush: all cross-barrier data uses agent-scope
// atomics (write-through to MALL). __syncthreads() drains vmcnt (compiler emits
// s_waitcnt vmcnt(0) before s_barrier), so stores are MALL-visible before the
// relaxed arrive.
__device__ __forceinline__ void gbar(int* ctr, int target) {
    __syncthreads();
    if (threadIdx.x == 0) {
        __hip_atomic_fetch_add(ctr, 1, __ATOMIC_RELAXED, __HIP_MEMORY_SCOPE_AGENT);
        while (__hip_atomic_load(ctr, __ATOMIC_RELAXED, __HIP_MEMORY_SCOPE_AGENT) < target)
            __builtin_amdgcn_s_sleep(1);
    }
    __syncthreads();
}

// ---- prep: combined weights -> bf16 hi/lo limbs; W_win transpose (f32) ----
__global__ void prep_weights(const float* __restrict__ Wx, const float* __restrict__ Wh,
                             const float* __restrict__ Wwin,
                             unsigned short* __restrict__ wcb, float* __restrict__ wwt) {
    int i = blockIdx.x*256 + threadIdx.x;
    const int n1 = 2048*KP;                       // 1,245,184
    if (i < n1) {
        int col = i / KP, k = i % KP;
        float v;
        if (k < 80)       v = Wx[(3+k)*2048 + col];    // w rows
        else if (k < 83)  v = Wx[(k-80)*2048 + col];   // x rows
        else if (k < 96)  v = 0.f;                     // pad
        else              v = Wh[(k-96)*2048 + col];   // h rows
        unsigned short hi = f2b(v);
        wcb[i]      = hi;
        wcb[WL + i] = f2b(v - b2f(hi));
    } else {
        int j = i - n1;
        if (j < 30*512) {
            int c = j >> 9, k = j & 511;
            wwt[j] = Wwin[k*30 + c];                  // [c][k] f32
        }
    }
}

// ---- prep: A-matrix double-buffer (hi/lo), barrier counter ----
__global__ void prep_state(const float* __restrict__ x, unsigned short* __restrict__ amat,
                           int* __restrict__ ctr) {
    int i = blockIdx.x*256 + threadIdx.x;
    const int n1 = 2*Bb*KP;           // (buf, r, k) = 155,648
    if (i < n1) {
        int buf = i / (Bb*KP);
        int r   = (i % (Bb*KP)) / KP;
        int k   = i % KP;
        float v = 0.f;
        if (buf == 0 && k >= 80 && k < 83) v = x[r*(Tt*3) + (k-80)];   // x[:,0,:]
        unsigned short hi = f2b(v);
        amat[(buf*2 + 0)*AL + r*KP + k] = hi;
        amat[(buf*2 + 1)*AL + r*KP + k] = f2b(v - b2f(hi));
    } else if (i == n1) {
        ctr[0] = 0;
    }
}

__global__ __launch_bounds__(256, 1) void rnn_main(
    const float* __restrict__ x,      // [128][800][3]
    const float* __restrict__ sent,   // [128][64][80]
    const int*   __restrict__ slen,   // [128]
    const float* __restrict__ bias,   // [2048]
    const float* __restrict__ bwin,   // [30]
    const unsigned short* __restrict__ wcb,   // 2 limb x [2048][608]
    const float* __restrict__ wwt,            // [30][512] f32
    unsigned short* __restrict__ amat,        // 2 buf x 2 limb x [128][608]
    int* __restrict__ ctr,
    float* __restrict__ out)
{
    __shared__ unsigned short ldsB[2*16*KSTR]; // weight cols hi|lo  40,448 B
    __shared__ float ldsWw[30*WWS];            // W_win^T [c][k]     62,040 B
    __shared__ float ldsSent[Uu*Cc];           // sentence row f32   20,480 B
    __shared__ float ldsH[512];                // h row f32
    __shared__ float ldsWinP[256];             // win partials [q*32+c]
    __shared__ float ldsWin[32];
    __shared__ float ldsPhi[Uu];
    __shared__ float ldsBias[16];
    __shared__ float ldsBwin[32];
    __shared__ float ldsKap[16];               // block-private kappa

    const int blk  = blockIdx.x;
    const int tid  = threadIdx.x;
    const int wave = tid >> 6;
    const int lane = tid & 63;
    const int l15  = lane & 15;
    const int lhi  = lane >> 4;
    const int row  = blk;               // phase-B batch row

    // ---- one-time LDS fills ----
    for (int idx = tid; idx < 16*76; idx += 256) {
        int cc = idx / 76, k8 = idx % 76;
        int col = (cc >> 2)*512 + blk*4 + (cc & 3);   // gate*512 + n
        *(short8*)&ldsB[cc*KSTR + k8*8]       = *(const short8*)&wcb[col*KP + k8*8];
        *(short8*)&ldsB[LBL + cc*KSTR + k8*8] = *(const short8*)&wcb[WL + col*KP + k8*8];
    }
    for (int idx = tid; idx < 30*512; idx += 256) {
        int c = idx >> 9, k = idx & 511;
        ldsWw[c*WWS + k] = wwt[idx];
    }
    for (int idx = tid; idx < Uu*Cc; idx += 256)
        ldsSent[idx] = sent[row*(Uu*Cc) + idx];
    if (tid < 16) ldsBias[tid] = bias[(tid>>2)*512 + blk*4 + (tid&3)];
    if (tid < 30) ldsBwin[tid] = bwin[tid];
    if (tid < 16) ldsKap[tid] = 0.f;
    __syncthreads();

    const int myLen = slen[row];
    float c_reg[2][4] = {{0.f,0.f,0.f,0.f},{0.f,0.f,0.f,0.f}};
    int bar_target = 0;

    for (int t = 0; t < Tt; ++t) {
        const int cur = t & 1, nxt = cur ^ 1;
        const unsigned short* aH  = amat + cur*ABUF;
        const unsigned short* aLo = aH + AL;
        unsigned short*       wH  = amat + nxt*ABUF;
        unsigned short*       wLo = wH + AL;

        // ============ Phase A: z = [w,x,h] @ Wc (split bf16 hi/lo), gates, h ============
        #pragma unroll
        for (int mi = 0; mi < 2; ++mi) {
            const int mt = wave*2 + mi;
            f32x4 acc0 = {0.f,0.f,0.f,0.f};    // hi*hi
            f32x4 acc1 = {0.f,0.f,0.f,0.f};    // hi*lo + lo*hi
            const u64* arH = (const u64*)(aH  + (mt*16 + l15)*KP) + lhi*2;
            const u64* arL = (const u64*)(aLo + (mt*16 + l15)*KP) + lhi*2;
            const unsigned short* brH = ldsB + l15*KSTR + lhi*8;
            const unsigned short* brL = ldsB + LBL + l15*KSTR + lhi*8;
            #pragma unroll
            for (int kt = 0; kt < 19; ++kt) {
                u64 a0 = ald(arH + kt*8), a1 = ald(arH + kt*8 + 1);
                u64 b0 = ald(arL + kt*8), b1 = ald(arL + kt*8 + 1);
                short8 ah, al;
                __builtin_memcpy(&ah, &a0, 8); __builtin_memcpy((char*)&ah + 8, &a1, 8);
                __builtin_memcpy(&al, &b0, 8); __builtin_memcpy((char*)&al + 8, &b1, 8);
                short8 bh = *(const short8*)(brH + kt*32);
                short8 bl = *(const short8*)(brL + kt*32);
                acc0 = __builtin_amdgcn_mfma_f32_16x16x32_bf16(ah, bh, acc0, 0, 0, 0);
                acc1 = __builtin_amdgcn_mfma_f32_16x16x32_bf16(ah, bl, acc1, 0, 0, 0);
                acc1 = __builtin_amdgcn_mfma_f32_16x16x32_bf16(al, bh, acc1, 0, 0, 0);
            }
            const float bv = ldsBias[l15];
            #pragma unroll
            for (int r = 0; r < 4; ++r) {
                float v   = acc0[r] + acc1[r] + bv;
                float t4  = __shfl_xor(v, 4);
                float t8  = __shfl_xor(v, 8);
                float t12 = __shfl_xor(v, 12);
                // lanes with l15<4: zi=v zf=t4 zg=t8 zo=t12
                float ig = sigm(v), fg = sigm(t4), gg = tanhf(t8), og = sigm(t12);
                float cn = fg * c_reg[mi][r] + ig * gg;
                c_reg[mi][r] = cn;
                float h = og * tanhf(cn);
                if (l15 < 4) {
                    int br = mt*16 + lhi*4 + r;
                    int n  = blk*4 + l15;
                    unsigned short hb = f2b(h);
                    ast2(wH  + br*KP + 96 + n, hb);
                    ast2(wLo + br*KP + 96 + n, f2b(h - b2f(hb)));
                    out[(size_t)(br*Tt + t)*Nn + n] = h;
                }
            }
        }
        bar_target += NBLK; gbar(ctr, bar_target);

        // ============ Phase B: win, phi, w for batch row = blk ============
        if (tid < 128) {   // stage h row (hi+lo -> f32) into LDS; 512 shorts = 128 u64
            u64 vh = ald((const u64*)(wH  + row*KP + 96) + tid);
            u64 vl = ald((const u64*)(wLo + row*KP + 96) + tid);
            unsigned short ph[4], pl[4];
            __builtin_memcpy(ph, &vh, 8); __builtin_memcpy(pl, &vl, 8);
            #pragma unroll
            for (int j = 0; j < 4; ++j)
                ldsH[tid*4 + j] = b2f(ph[j]) + b2f(pl[j]);
        }
        __syncthreads();
        {   // win partials: c = tid&31 (<30), k-chunk q = tid>>5
            int c = tid & 31, q = tid >> 5;
            if (c < 30) {
                const float* wwc = &ldsWw[c*WWS + q*64];
                const float* hh  = &ldsH[q*64];
                float s = 0.f;
                #pragma unroll
                for (int k = 0; k < 64; ++k) s += hh[k]*wwc[k];
                ldsWinP[q*32 + c] = s;
            } else if (tid == 30 && t + 1 < Tt) {     // prefetch x_{t+1} -> k 80..83
                const float* xp = &x[((size_t)row*Tt + (t+1))*3];
                unsigned short hi4[4], lo4[4];
                #pragma unroll
                for (int j = 0; j < 3; ++j) {
                    float xv = xp[j];
                    hi4[j] = f2b(xv); lo4[j] = f2b(xv - b2f(hi4[j]));
                }
                hi4[3] = 0; lo4[3] = 0;
                u64 hv, lv; __builtin_memcpy(&hv, hi4, 8); __builtin_memcpy(&lv, lo4, 8);
                ast8((u64*)(wH  + row*KP + 80), hv);
                ast8((u64*)(wLo + row*KP + 80), lv);
            }
        }
        __syncthreads();
        if (tid < 30) {
            float s = 0.f;
            #pragma unroll
            for (int q = 0; q < 8; ++q) s += ldsWinP[q*32 + tid];
            ldsWin[tid] = s + ldsBwin[tid];
        }
        __syncthreads();
        if (tid < 64) {                        // phi over u = tid
            float u1 = (float)tid + 1.0f;
            float phi = 0.f;
            #pragma unroll
            for (int k = 0; k < 10; ++k) {
                float a  = expf(ldsWin[k]);
                float be = expf(ldsWin[10+k]);
                float kn = ldsKap[k] + expf(ldsWin[20+k]);
                float d  = kn - u1;
                phi += a * expf(-be * d * d);
            }
            if (tid >= myLen) phi = 0.f;
            ldsPhi[tid] = phi;
            out[OUT_PHI + (size_t)(row*Tt + t)*Uu + tid] = phi;
            if (tid < 10)
                ldsKap[tid] += expf(ldsWin[20+tid]);   // after reads (wave-lockstep)
        }
        __syncthreads();
        if (tid < 80) {                        // w = phi . sent -> k 0..79
            float s = 0.f;
            #pragma unroll
            for (int u = 0; u < Uu; ++u)
                s += ldsPhi[u] * ldsSent[u*Cc + tid];
            out[OUT_W + (size_t)(row*Tt + t)*Cc + tid] = s;
            unsigned short hb = f2b(s);
            ast2(wH  + row*KP + tid, hb);
            ast2(wLo + row*KP + tid, f2b(s - b2f(hb)));
        }
        bar_target += NBLK; gbar(ctr, bar_target);
    }
}

extern "C" void kernel_launch(void* const* d_in, const int* in_sizes, int n_in,
                              void* d_out, int out_size, void* d_ws, size_t ws_size,
                              hipStream_t stream) {
    (void)in_sizes; (void)n_in; (void)out_size; (void)ws_size;
    const float* x    = (const float*)d_in[0];
    const float* sent = (const float*)d_in[1];
    const int*   sl   = (const int*)d_in[2];
    const float* Wx   = (const float*)d_in[3];
    const float* Wh   = (const float*)d_in[4];
    const float* bias = (const float*)d_in[5];
    const float* Wwin = (const float*)d_in[6];
    const float* bwin = (const float*)d_in[7];

    char* ws = (char*)d_ws;
    unsigned short* wcb  = (unsigned short*)(ws + WS_WCB);
    unsigned short* amat = (unsigned short*)(ws + WS_AMAT);
    float* wwt = (float*)(ws + WS_WWT);
    int*   ctr = (int*)(ws + WS_CTR);
    float* out = (float*)d_out;

    {
        int total = 2048*KP + 30*512;
        prep_weights<<<(total + 255)/256, 256, 0, stream>>>(Wx, Wh, Wwin, wcb, wwt);
    }
    {
        int total = 2*Bb*KP + 1;
        prep_state<<<(total + 255)/256, 256, 0, stream>>>(x, amat, ctr);
    }
    rnn_main<<<NBLK, 256, 0, stream>>>(x, sent, sl, bias, bwin, wcb, wwt, amat, ctr, out);
}